// Round 6
// baseline (56.479 us; speedup 1.0000x reference)
//
#include <hip/hip_runtime.h>

#define BLK 1024
#define NSLOT 1028   // slot(j) = j+2 for angle/edge index j in [-2 .. 1025]

// minimax atan2, max err ~2e-6 rad; inputs never both zero here
__device__ __forceinline__ float fast_atan2f(float y, float x) {
    float ax = __builtin_fabsf(x), ay = __builtin_fabsf(y);
    float mx = fmaxf(ax, ay), mn = fminf(ax, ay);
    float a  = mn * __builtin_amdgcn_rcpf(mx);
    float s  = a * a;
    float r  = fmaf(s, -0.0117212f,  0.05265332f);
    r = fmaf(s, r, -0.11643287f);
    r = fmaf(s, r,  0.19354346f);
    r = fmaf(s, r, -0.33262347f);
    r = fmaf(s, r,  0.99997726f);
    r *= a;
    if (ay > ax)  r = 1.57079637f - r;
    if (x < 0.0f) r = 3.14159274f - r;
    return copysignf(r, y);
}

// shared integrator => bit-identical codegen for all three node replicas
__device__ __forceinline__ void integ(float2& p, float2& v, float fx, float fy) {
    float tx = fmaf(-2.0f, v.x, fx);
    float ty = fmaf(-2.0f, v.y, fy);
    v.x = fmaf(0.001f, tx, v.x);
    v.y = fmaf(0.001f, ty, v.y);
    p.x = fmaf(0.001f, v.x, p.x);
    p.y = fmaf(0.001f, v.y, p.y);
}

__global__ __launch_bounds__(BLK)
void equil_kernel(const float* __restrict__ pos0,
                  const float* __restrict__ tip_pos,
                  const float* __restrict__ thetas_ss,
                  const int*   __restrict__ buckle,
                  const float* __restrict__ kstiff_p,
                  const float* __restrict__ ksoft_p,
                  const float* __restrict__ kstretch_p,
                  float* __restrict__ out)
{
    // slot j+2 holds {P_j.x, P_j.y, B_j.x, B_j.y}; double-buffered
    __shared__ float4 PB0[NSLOT];
    __shared__ float4 PB1[NSLOT];

    const int b = blockIdx.x;
    const int t = threadIdx.x;
    const float k_str  = kstretch_p[0];
    const float k_sd   = kstiff_p[0] - ksoft_p[0];
    const float k4soft = 4.0f * ksoft_p[0];

    const float2* p0g = (const float2*)(pos0 + (size_t)b * 2052);
    // thread t tracks nodes t, t+1, t+2 redundantly in registers
    float2 pA = p0g[t];
    float2 pB = p0g[t + 1];
    float2 pC;
    if (t < 1023) pC = p0g[t + 2];
    else { pC.x = tip_pos[2*b]; pC.y = tip_pos[2*b+1]; }

    const float TH = thetas_ss[t];
    const int4 bk  = ((const int4*)buckle)[t];
    const float npl = (float)(bk.x + bk.y + bk.z + bk.w);
    float2 vA = make_float2(0.f,0.f), vB = vA, vC = vA;

    const bool updA = (t >= 2);       // node t    free iff 2<=t
    const bool updB = (t >= 1);       // node t+1  free iff t+1>=2
    const bool updC = (t <= 1022);    // node t+2  free iff t+2<=1024

    // zero the out-of-range slots (j=-2,-1,1025) in both buffers
    if (t < 2)   { PB0[t]    = make_float4(0,0,0,0); PB1[t]    = make_float4(0,0,0,0); }
    if (t == 2)  { PB0[1027] = make_float4(0,0,0,0); PB1[1027] = make_float4(0,0,0,0); }
    // (visible after the first in-step barrier; no extra sync needed)

#define STEP(BUF)                                                             \
    {                                                                         \
        float v1x = pB.x - pA.x, v1y = pB.y - pA.y;                           \
        float v2x = pC.x - pB.x, v2y = pC.y - pB.y;                           \
        float l2a = fmaf(v1x, v1x, v1y * v1y);                                \
        float l2b = fmaf(v2x, v2x, v2y * v2y);                                \
        float cr  = v1x * v2y - v1y * v2x;                                    \
        float dt_ = fmaf(v1x, v2x, v1y * v2y);                                \
        float theta = fast_atan2f(cr, dt_);                                   \
        float cnt = (theta <  TH ? npl       : 0.f)                           \
                  + (theta > -TH ? 4.f - npl : 0.f);                          \
        float K = fmaf(cnt, k_sd, k4soft);                                    \
        float m = K * (theta - TH);                                           \
        float ila = __builtin_amdgcn_rsqf(l2a);                               \
        float ilb = __builtin_amdgcn_rsqf(l2b);                               \
        float m1 = m * ila * ila;                                             \
        float m2 = m * ilb * ilb;                                             \
        float Bx = -m2 * v2y, By = m2 * v2x;                                  \
        float sca = k_str * (1.0f - ila);                                     \
        float Px = fmaf(sca, v1x,  m1 * v1y);                                 \
        float Py = fmaf(sca, v1y, -m1 * v1x);                                 \
        BUF[t + 2] = make_float4(Px, Py, Bx, By);                             \
        if (t == 1023) {                                                      \
            float scb = k_str * (1.0f - ilb);                                 \
            BUF[1026] = make_float4(scb * v2x, scb * v2y, 0.f, 0.f);          \
        }                                                                     \
        __syncthreads();                                                      \
        float4 jm2 = BUF[t];       /* j=t-2 */                                \
        float4 jm1 = BUF[t + 1];   /* j=t-1 */                                \
        float4 jp1 = BUF[t + 3];   /* j=t+1 */                                \
        float4 jp2 = BUF[t + 4];   /* j=t+2 */                                \
        float f0x = Px    - (jm1.x - jm1.z) - jm2.z;                          \
        float f0y = Py    - (jm1.y - jm1.w) - jm2.w;                          \
        float f1x = jp1.x - (Px    - Bx)    - jm1.z;                          \
        float f1y = jp1.y - (Py    - By)    - jm1.w;                          \
        float f2x = jp2.x - (jp1.x - jp1.z) - Bx;                             \
        float f2y = jp2.y - (jp1.y - jp1.w) - By;                             \
        if (updA) integ(pA, vA, f0x, f0y);                                    \
        if (updB) integ(pB, vB, f1x, f1y);                                    \
        if (updC) integ(pC, vC, f2x, f2y);                                    \
    }

    for (int s = 0; s < 32; ++s) {
        STEP(PB0);
        STEP(PB1);
    }
#undef STEP

    // ---- epilogue ----
    float2* o = (float2*)(out + (size_t)b * 2052);
    o[t + 2] = pC;            // t=1023 writes node 1025 = tip
    if (t == 0) { o[0] = pA; o[1] = pB; }
}

extern "C" void kernel_launch(void* const* d_in, const int* in_sizes, int n_in,
                              void* d_out, int out_size, void* d_ws, size_t ws_size,
                              hipStream_t stream) {
    const float* pos0   = (const float*)d_in[0];
    const float* tip    = (const float*)d_in[1];
    const float* thetas = (const float*)d_in[2];
    const int*   buckle = (const int*)  d_in[3];
    const float* ks     = (const float*)d_in[4];
    const float* ko     = (const float*)d_in[5];
    const float* kr     = (const float*)d_in[6];
    float* out = (float*)d_out;
    hipLaunchKernelGGL(equil_kernel, dim3(256), dim3(BLK), 0, stream,
                       pos0, tip, thetas, buckle, ks, ko, kr, out);
}

// Round 7
// 47.634 us; speedup vs baseline: 1.1857x; 1.1857x over previous
//
#include <hip/hip_runtime.h>

#define BLK 512
typedef float v2f __attribute__((ext_vector_type(2)));

__device__ __forceinline__ v2f vs(float s) { return (v2f){s, s}; }

// minimax atan2, max err ~2e-6 rad; inputs never both zero here
__device__ __forceinline__ float fast_atan2f(float y, float x) {
    float ax = __builtin_fabsf(x), ay = __builtin_fabsf(y);
    float mx = fmaxf(ax, ay), mn = fminf(ax, ay);
    float a  = mn * __builtin_amdgcn_rcpf(mx);
    float s  = a * a;
    float r  = fmaf(s, -0.0117212f,  0.05265332f);
    r = fmaf(s, r, -0.11643287f);
    r = fmaf(s, r,  0.19354346f);
    r = fmaf(s, r, -0.33262347f);
    r = fmaf(s, r,  0.99997726f);
    r *= a;
    if (ay > ax)  r = 1.57079637f - r;
    if (x < 0.0f) r = 3.14159274f - r;
    return copysignf(r, y);
}

__global__ __launch_bounds__(BLK)
void equil_kernel(const float* __restrict__ pos0,
                  const float* __restrict__ tip_pos,
                  const float* __restrict__ thetas_ss,
                  const int*   __restrict__ buckle,
                  const float* __restrict__ kstiff_p,
                  const float* __restrict__ ksoft_p,
                  const float* __restrict__ kstretch_p,
                  float* __restrict__ out)
{
    // thread t: angles 2t,2t+1; owns nodes 2t+2 (pA, always free), 2t+3 (pB, free unless t=511)
    __shared__ float4 Pos4[513];   // slot k: nodes 2k+2, 2k+3
    __shared__ float4 PP4[513];    // slot u: {P_2u, P_2u+1}; slot 512: {P_1024, P_1024}
    __shared__ float2 Q2[513];     // slot u: Q_2u

    const int b = blockIdx.x;
    const int t = threadIdx.x;
    const float k_str  = kstretch_p[0];
    const float k_sd   = kstiff_p[0] - ksoft_p[0];
    const float k4soft = 4.0f * ksoft_p[0];

    const float2* p0g = (const float2*)(pos0 + (size_t)b * 2052);
    float2 c0f = p0g[0], c1f = p0g[1];
    const v2f c0 = (v2f){c0f.x, c0f.y};
    const v2f c1 = (v2f){c1f.x, c1f.y};

    float2 a_ = p0g[2*t + 2];
    v2f pA = (v2f){a_.x, a_.y};
    v2f pB;
    if (t < 511) { float2 b_ = p0g[2*t + 3]; pB = (v2f){b_.x, b_.y}; }
    else         { pB = (v2f){tip_pos[2*b], tip_pos[2*b+1]}; }

    const float2 th2 = ((const float2*)thetas_ss)[t];
    const float TH0 = th2.x, TH1 = th2.y;
    const int4 bk0 = ((const int4*)buckle)[2*t];
    const int4 bk1 = ((const int4*)buckle)[2*t + 1];
    const float npl0 = (float)(bk0.x + bk0.y + bk0.z + bk0.w);
    const float npl1 = (float)(bk1.x + bk1.y + bk1.z + bk1.w);

    v2f vA = vs(0.f), vB = vs(0.f);

    Pos4[t] = make_float4(pA.x, pA.y, pB.x, pB.y);
    if (t == 0) Q2[512] = make_float2(0.f, 0.f);
    __syncthreads();

    for (int s = 0; s < 64; ++s) {
        // ---- phase AB: angles 2t (e0,e1) and 2t+1 (e1,e2) ----
        float4 L = Pos4[t == 0 ? 0 : t - 1];
        v2f nL0 = (t == 0) ? c0 : (v2f){L.x, L.y};
        v2f nL1 = (t == 0) ? c1 : (v2f){L.z, L.w};
        v2f e0 = nL1 - nL0;
        v2f e1 = pA - nL1;
        v2f e2 = pB - pA;
        float l20 = fmaf(e0.x, e0.x, e0.y * e0.y);
        float l21 = fmaf(e1.x, e1.x, e1.y * e1.y);
        float l22 = fmaf(e2.x, e2.x, e2.y * e2.y);
        float ila0 = __builtin_amdgcn_rsqf(l20);
        float ila1 = __builtin_amdgcn_rsqf(l21);
        float ila2 = __builtin_amdgcn_rsqf(l22);

        // angle 2t
        float cr0 = e0.x * e1.y - e0.y * e1.x;
        float dt0 = fmaf(e0.x, e1.x, e0.y * e1.y);
        float th_0 = fast_atan2f(cr0, dt0);
        float cnt0 = (th_0 <  TH0 ? npl0       : 0.f)
                   + (th_0 > -TH0 ? 4.f - npl0 : 0.f);
        float m0 = fmaf(cnt0, k_sd, k4soft) * (th_0 - TH0);
        // angle 2t+1
        float cr1 = e1.x * e2.y - e1.y * e2.x;
        float dt1 = fmaf(e1.x, e2.x, e1.y * e2.y);
        float th_1 = fast_atan2f(cr1, dt1);
        float cnt1 = (th_1 <  TH1 ? npl1       : 0.f)
                   + (th_1 > -TH1 ? 4.f - npl1 : 0.f);
        float m1 = fmaf(cnt1, k_sd, k4soft) * (th_1 - TH1);

        float il20 = ila0 * ila0, il21 = ila1 * ila1, il22 = ila2 * ila2;
        float ca0 = m0 * il20, cb0 = m0 * il21;
        float ca1 = m1 * il21, cb1 = m1 * il22;
        v2f rot0 = (v2f){e0.y, -e0.x};
        v2f rot1 = (v2f){e1.y, -e1.x};
        v2f rot2 = (v2f){e2.y, -e2.x};
        float sc0 = k_str * (1.0f - ila0);
        float sc1 = k_str * (1.0f - ila1);
        v2f P0 = vs(sc0) * e0 + vs(ca0) * rot0;    // S_2t   + a_2t
        v2f B0 = vs(-cb0) * rot1;                  // b_2t
        v2f Q0 = P0 - B0;
        v2f P1 = vs(sc1) * e1 + vs(ca1) * rot1;    // S_2t+1 + a_2t+1
        v2f B1 = vs(-cb1) * rot2;                  // b_2t+1
        v2f Q1 = P1 - B1;

        PP4[t] = make_float4(P0.x, P0.y, P1.x, P1.y);
        Q2[t]  = make_float2(Q0.x, Q0.y);
        if (t == 511) {   // P[1024] = S_1024 (stretch-only slot for edge 1024)
            float sc2 = k_str * (1.0f - ila2);
            PP4[512] = make_float4(sc2 * e2.x, sc2 * e2.y, sc2 * e2.x, sc2 * e2.y);
        }
        __syncthreads();

        // ---- phase C: forces + integration ----
        float4 Pn  = PP4[t + 1];     // {P_{2t+2}, P_{2t+3}}
        float2 Qn2 = Q2[t + 1];      // Q_{2t+2}
        v2f f0 = ((v2f){Pn.x, Pn.y} - Q1) - B0;                  // node 2t+2
        v2f f1 = ((v2f){Pn.z, Pn.w} - (v2f){Qn2.x, Qn2.y}) - B1; // node 2t+3
        vA = vA + vs(0.001f) * (f0 - vs(2.0f) * vA);
        pA = pA + vs(0.001f) * vA;
        if (t < 511) {
            vB = vB + vs(0.001f) * (f1 - vs(2.0f) * vB);
            pB = pB + vs(0.001f) * vB;
        }
        Pos4[t] = make_float4(pA.x, pA.y, pB.x, pB.y);
        __syncthreads();
    }

    // ---- epilogue ----
    float4* o4 = (float4*)(out + (size_t)b * 2052);
    o4[t + 1] = make_float4(pA.x, pA.y, pB.x, pB.y);
    if (t == 0) o4[0] = make_float4(c0.x, c0.y, c1.x, c1.y);
}

extern "C" void kernel_launch(void* const* d_in, const int* in_sizes, int n_in,
                              void* d_out, int out_size, void* d_ws, size_t ws_size,
                              hipStream_t stream) {
    const float* pos0   = (const float*)d_in[0];
    const float* tip    = (const float*)d_in[1];
    const float* thetas = (const float*)d_in[2];
    const int*   buckle = (const int*)  d_in[3];
    const float* ks     = (const float*)d_in[4];
    const float* ko     = (const float*)d_in[5];
    const float* kr     = (const float*)d_in[6];
    float* out = (float*)d_out;
    hipLaunchKernelGGL(equil_kernel, dim3(256), dim3(BLK), 0, stream,
                       pos0, tip, thetas, buckle, ks, ko, kr, out);
}